// Round 5
// baseline (293.140 us; speedup 1.0000x reference)
//
#include <hip/hip_runtime.h>
#include <hip/hip_bf16.h>

typedef _Float16 half8 __attribute__((ext_vector_type(8)));
typedef _Float16 half4 __attribute__((ext_vector_type(4)));
typedef float floatx4 __attribute__((ext_vector_type(4)));

#define EMBED 1024
#define SEQ   2048
#define BATCH 32
#define M_TOT (BATCH * SEQ)   // 65536 rows
#define KDIM  1024
#define NDIM  1024

// async global->LDS, 16B per lane, dest = wave-uniform base + lane*16
#define GLOAD16(g, l) __builtin_amdgcn_global_load_lds(                      \
    (const __attribute__((address_space(1))) void*)(g),                      \
    (__attribute__((address_space(3))) void*)(l), 16, 0, 0)

// ---------------------------------------------------------------------------
// Kernel 1: transpose + convert W[K][N] fp32 -> Wt[N][K] fp16
// ---------------------------------------------------------------------------
__global__ void transpose_w_kernel(const float* __restrict__ W,
                                   _Float16* __restrict__ Wt) {
    __shared__ float t[32][33];
    const int kt = blockIdx.x * 32;
    const int nt = blockIdx.y * 32;
    #pragma unroll
    for (int i = 0; i < 4; ++i)
        t[threadIdx.y + 8 * i][threadIdx.x] =
            W[(size_t)(kt + threadIdx.y + 8 * i) * NDIM + nt + threadIdx.x];
    __syncthreads();
    #pragma unroll
    for (int i = 0; i < 4; ++i)
        Wt[(size_t)(nt + threadIdx.y + 8 * i) * KDIM + kt + threadIdx.x] =
            (_Float16)t[threadIdx.x][threadIdx.y + 8 * i];
}

// ---------------------------------------------------------------------------
// Kernel 2: zero scores + out
// ---------------------------------------------------------------------------
__global__ void zero_kernel(float* __restrict__ scores, float* __restrict__ out) {
    const int i = blockIdx.x * 256 + threadIdx.x;
    if (i < M_TOT) scores[i] = 0.0f;
    if (i < BATCH * EMBED) out[i] = 0.0f;
}

// ---------------------------------------------------------------------------
// Kernel 2b: convert x fp32 -> fp16 (64M elements)
// ---------------------------------------------------------------------------
__global__ __launch_bounds__(256) void cvt_x_kernel(const float* __restrict__ x,
                                                    _Float16* __restrict__ x16) {
    const size_t stride = (size_t)gridDim.x * 256 * 8;
    for (size_t i = ((size_t)blockIdx.x * 256 + threadIdx.x) * 8;
         i < (size_t)M_TOT * KDIM; i += stride) {
        const float4 a = *(const float4*)(x + i);
        const float4 b = *(const float4*)(x + i + 4);
        half8 h;
        h[0] = (_Float16)a.x; h[1] = (_Float16)a.y; h[2] = (_Float16)a.z; h[3] = (_Float16)a.w;
        h[4] = (_Float16)b.x; h[5] = (_Float16)b.y; h[6] = (_Float16)b.z; h[7] = (_Float16)b.w;
        *(half8*)(x16 + i) = h;
    }
}

// ---------------------------------------------------------------------------
// Kernel 3: fused scores GEMM, 256x256 tile, BK=64, 512 threads (8 waves 2Mx4N).
// One barrier + one vmcnt drain per K-step covering 512 MFMA/block (T3 minimum
// recipe at m201 geometry). LDS [128 rows][64 halves] per half-tile would be a
// 16-way read conflict if linear; fixed by XOR slot swizzle p = s ^ (row&7),
// applied on the GLOBAL source (stage) and the ds_read address (both-sides).
// gload_lds dest stays linear. XCD chunk swizzle for A-panel L2/L3 locality.
// ---------------------------------------------------------------------------
__global__ __launch_bounds__(512, 2) void score_gemm4(
    const _Float16* __restrict__ x16, const _Float16* __restrict__ Wt,
    const float* __restrict__ bias, const float* __restrict__ ctx,
    float* __restrict__ scores) {
    __shared__ _Float16 As[2][256 * 64];    // 32KB per buf
    __shared__ _Float16 Bs[2][256 * 64];    // total 128KB

    const int tid = threadIdx.x;
    const int lane = tid & 63;
    const int w = tid >> 6;       // 0..7
    const int wm = w >> 2;        // 2 row groups of 128
    const int wn = w & 3;         // 4 col groups of 64

    // grid 1024 = 256 bm x 4 bn; XCD chunk swizzle (bijective: 8 x 128)
    const int nb = ((blockIdx.x & 7) << 7) | (blockIdx.x >> 3);
    const int bm = nb >> 2;
    const int bn = nb & 3;

    // ---- staging geometry ----
    // instr i (0..3): chunk j = i*8 + w covers tile-rows [j*8, j*8+8), 1024B LDS.
    // lane l -> row j*8 + (l>>3), physical 16B slot l&7 (linear dest);
    // global 16B slot s = (l&7) ^ (l>>3)  (pre-swizzled source).
    const int srow  = lane >> 3;                 // 0..7
    const int sslot = (lane & 7) ^ srow;         // 0..7
    const _Float16* Ab = x16 + (size_t)(bm * 256) * KDIM;
    const _Float16* Bb = Wt  + (size_t)(bn * 256) * KDIM;

    #define STAGE(buf, kt)                                                         \
        {                                                                          \
            _Pragma("unroll")                                                      \
            for (int i = 0; i < 4; ++i) {                                          \
                const int j = i * 8 + w;                                           \
                const size_t go = (size_t)(j * 8 + srow) * KDIM + (kt) * 64 + sslot * 8; \
                GLOAD16(Ab + go, &As[buf][j * 512]);                               \
                GLOAD16(Bb + go, &Bs[buf][j * 512]);                               \
            }                                                                      \
        }

    // ---- frag read geometry ----
    // row r = base + frow; col slot s = ks*4 + (lane>>4); physical p = s ^ (r&7)
    const int frow = lane & 15;
    const int fsw  = frow & 7;
    const int fhi  = lane >> 4;    // 0..3

    floatx4 acc[8][4] = {};

    STAGE(0, 0);
    __syncthreads();

    for (int kt = 0; kt < 16; ++kt) {
        const int cur = kt & 1;
        if (kt < 15) STAGE(cur ^ 1, kt + 1);   // in flight under this K-step

        #pragma unroll
        for (int ks = 0; ks < 2; ++ks) {
            const int sp = ks * 4 + fhi;
            half8 bfr[4];
            #pragma unroll
            for (int ni = 0; ni < 4; ++ni) {
                const int r = wn * 64 + ni * 16 + frow;
                bfr[ni] = *(const half8*)&Bs[cur][r * 64 + ((sp ^ fsw) * 8)];
            }
            __builtin_amdgcn_s_setprio(1);
            #pragma unroll
            for (int mi = 0; mi < 8; ++mi) {
                const int r = wm * 128 + mi * 16 + frow;
                const half8 a = *(const half8*)&As[cur][r * 64 + ((sp ^ fsw) * 8)];
                #pragma unroll
                for (int ni = 0; ni < 4; ++ni)
                    acc[mi][ni] = __builtin_amdgcn_mfma_f32_16x16x32_f16(
                        a, bfr[ni], acc[mi][ni], 0, 0, 0);
            }
            __builtin_amdgcn_s_setprio(0);
        }
        __syncthreads();   // drains this K-step's STAGE (vmcnt) + all ds reads
    }
    #undef STAGE

    // ---- epilogue: fast tanh + ctx dot + 16-lane reduce + atomic ----
    float bv[4], cv[4];
    #pragma unroll
    for (int ni = 0; ni < 4; ++ni) {
        const int col = bn * 256 + wn * 64 + ni * 16 + frow;
        bv[ni] = bias[col];
        cv[ni] = ctx[col];
    }
    #pragma unroll
    for (int mi = 0; mi < 8; ++mi) {
        #pragma unroll
        for (int j = 0; j < 4; ++j) {
            float partial = 0.0f;
            #pragma unroll
            for (int ni = 0; ni < 4; ++ni) {
                const float v = acc[mi][ni][j] + bv[ni];
                const float e = __expf(2.0f * v);          // tanh(v)=1-2/(e^{2v}+1)
                const float t = 1.0f - 2.0f * __builtin_amdgcn_rcpf(e + 1.0f);
                partial += t * cv[ni];
            }
            #pragma unroll
            for (int off = 1; off < 16; off <<= 1)
                partial += __shfl_xor(partial, off, 64);
            if (frow == 0) {
                const int rowg = bm * 256 + wm * 128 + mi * 16 + fhi * 4 + j;
                atomicAdd(&scores[rowg], partial);
            }
        }
    }
}

// ---------------------------------------------------------------------------
// Fallback GEMM (ws too small for x16): reg-staged fp32 path.
// ---------------------------------------------------------------------------
__global__ __launch_bounds__(256) void score_gemm_f32(
    const float* __restrict__ A32p, const _Float16* __restrict__ Wt,
    const float* __restrict__ bias, const float* __restrict__ ctx,
    float* __restrict__ scores) {
    __shared__ _Float16 As[128 * 64];
    __shared__ _Float16 Bs[128 * 64];

    const int bid = blockIdx.x;
    const int bm = bid >> 3;
    const int bn = bid & 7;
    const int tid = threadIdx.x;
    const int lane = tid & 63;
    const int wid = tid >> 6;
    const int wm = wid >> 1;
    const int wn = wid & 1;

    const int c = tid & 7;
    const int r0 = tid >> 3;
    const int swz = (r0 & 7) << 3;
    const int wcol = (c * 8) ^ swz;

    float4 aF[4][2];
    int4   bR[4];

    #pragma unroll
    for (int i = 0; i < 4; ++i) {
        const int row = r0 + 32 * i;
        const float* p = A32p + (size_t)(bm * 128 + row) * KDIM + c * 8;
        aF[i][0] = *(const float4*)p;
        aF[i][1] = *(const float4*)(p + 4);
        bR[i] = *(const int4*)(Wt + (size_t)(bn * 128 + row) * KDIM + c * 8);
    }

    floatx4 acc[4][4] = {};

    for (int kt = 0; kt < KDIM / 64; ++kt) {
        __syncthreads();
        #pragma unroll
        for (int i = 0; i < 4; ++i) {
            const int row = r0 + 32 * i;
            half8 h;
            h[0] = (_Float16)aF[i][0].x; h[1] = (_Float16)aF[i][0].y;
            h[2] = (_Float16)aF[i][0].z; h[3] = (_Float16)aF[i][0].w;
            h[4] = (_Float16)aF[i][1].x; h[5] = (_Float16)aF[i][1].y;
            h[6] = (_Float16)aF[i][1].z; h[7] = (_Float16)aF[i][1].w;
            *(half8*)&As[row * 64 + wcol] = h;
            *(int4*)&Bs[row * 64 + wcol] = bR[i];
        }
        __syncthreads();

        if (kt + 1 < KDIM / 64) {
            #pragma unroll
            for (int i = 0; i < 4; ++i) {
                const int row = r0 + 32 * i;
                const float* p = A32p + (size_t)(bm * 128 + row) * KDIM + (kt + 1) * 64 + c * 8;
                aF[i][0] = *(const float4*)p;
                aF[i][1] = *(const float4*)(p + 4);
                bR[i] = *(const int4*)(Wt + (size_t)(bn * 128 + row) * KDIM + (kt + 1) * 64 + c * 8);
            }
        }

        #pragma unroll
        for (int s = 0; s < 2; ++s) {
            half8 afr[4], bfr[4];
            const int colr = s * 32 + (lane >> 4) * 8;
            #pragma unroll
            for (int m = 0; m < 4; ++m) {
                const int row = wm * 64 + m * 16 + (lane & 15);
                afr[m] = *(const half8*)&As[row * 64 + (colr ^ ((row & 7) << 3))];
            }
            #pragma unroll
            for (int n = 0; n < 4; ++n) {
                const int row = wn * 64 + n * 16 + (lane & 15);
                bfr[n] = *(const half8*)&Bs[row * 64 + (colr ^ ((row & 7) << 3))];
            }
            #pragma unroll
            for (int m = 0; m < 4; ++m)
                #pragma unroll
                for (int n = 0; n < 4; ++n)
                    acc[m][n] = __builtin_amdgcn_mfma_f32_16x16x32_f16(
                        afr[m], bfr[n], acc[m][n], 0, 0, 0);
        }
    }

    float bv[4], cv[4];
    #pragma unroll
    for (int n = 0; n < 4; ++n) {
        const int col = bn * 128 + wn * 64 + n * 16 + (lane & 15);
        bv[n] = bias[col];
        cv[n] = ctx[col];
    }
    #pragma unroll
    for (int m = 0; m < 4; ++m) {
        #pragma unroll
        for (int j = 0; j < 4; ++j) {
            float partial = 0.0f;
            #pragma unroll
            for (int n = 0; n < 4; ++n) {
                const float v = acc[m][n][j] + bv[n];
                const float e = __expf(2.0f * v);
                const float t = 1.0f - 2.0f * __builtin_amdgcn_rcpf(e + 1.0f);
                partial += t * cv[n];
            }
            #pragma unroll
            for (int off = 1; off < 16; off <<= 1)
                partial += __shfl_xor(partial, off, 64);
            if ((lane & 15) == 0) {
                const int rowg = bm * 128 + wm * 64 + m * 16 + (lane >> 4) * 4 + j;
                atomicAdd(&scores[rowg], partial);
            }
        }
    }
}

// ---------------------------------------------------------------------------
// Kernel 4: softmax over seq dim per batch. 32 blocks x 256 threads.
// ---------------------------------------------------------------------------
__global__ void softmax_kernel(const float* __restrict__ scores,
                               float* __restrict__ weights) {
    const int bb = blockIdx.x;
    const int tid = threadIdx.x;
    const float* s = scores + (size_t)bb * SEQ;
    float* w = weights + (size_t)bb * SEQ;

    __shared__ float red[8];

    float v[8];
    float mx = -1e30f;
    #pragma unroll
    for (int i = 0; i < 8; ++i) {
        v[i] = s[tid + i * 256];
        mx = fmaxf(mx, v[i]);
    }
    #pragma unroll
    for (int off = 1; off < 64; off <<= 1)
        mx = fmaxf(mx, __shfl_xor(mx, off, 64));
    const int wv = tid >> 6;
    if ((tid & 63) == 0) red[wv] = mx;
    __syncthreads();
    mx = fmaxf(fmaxf(red[0], red[1]), fmaxf(red[2], red[3]));

    float sum = 0.0f;
    #pragma unroll
    for (int i = 0; i < 8; ++i) {
        v[i] = __expf(v[i] - mx);
        sum += v[i];
    }
    #pragma unroll
    for (int off = 1; off < 64; off <<= 1)
        sum += __shfl_xor(sum, off, 64);
    if ((tid & 63) == 0) red[4 + wv] = sum;
    __syncthreads();
    sum = red[4] + red[5] + red[6] + red[7];
    const float inv = 1.0f / sum;
    #pragma unroll
    for (int i = 0; i < 8; ++i)
        w[tid + i * 256] = v[i] * inv;
}

// ---------------------------------------------------------------------------
// Kernel 5: weighted pooling (fp32 fallback).
// ---------------------------------------------------------------------------
__global__ __launch_bounds__(256) void pool_kernel(const float* __restrict__ x,
                                                   const float* __restrict__ weights,
                                                   float* __restrict__ out) {
    const int bb = blockIdx.x >> 4;
    const int sc = blockIdx.x & 15;
    const int tid = threadIdx.x;

    const float4* xb = (const float4*)(x + (size_t)bb * SEQ * EMBED) +
                       (size_t)(sc * 128) * (EMBED / 4) + tid;
    const float* wb = weights + (size_t)bb * SEQ + sc * 128;

    float ax = 0.f, ay = 0.f, az = 0.f, aw = 0.f;
    #pragma unroll 4
    for (int s = 0; s < 128; ++s) {
        const float wgt = wb[s];
        const float4 xv = xb[(size_t)s * (EMBED / 4)];
        ax += wgt * xv.x; ay += wgt * xv.y; az += wgt * xv.z; aw += wgt * xv.w;
    }
    float* o = out + (size_t)bb * EMBED + tid * 4;
    atomicAdd(o + 0, ax);
    atomicAdd(o + 1, ay);
    atomicAdd(o + 2, az);
    atomicAdd(o + 3, aw);
}

// ---------------------------------------------------------------------------
// Kernel 5b: weighted pooling (fp16 x16) — halves the read bytes.
// ---------------------------------------------------------------------------
__global__ __launch_bounds__(256) void pool16_kernel(const _Float16* __restrict__ x16,
                                                     const float* __restrict__ weights,
                                                     float* __restrict__ out) {
    const int bb = blockIdx.x >> 4;
    const int sc = blockIdx.x & 15;
    const int tid = threadIdx.x;

    const _Float16* xb = x16 + (size_t)bb * SEQ * EMBED +
                         (size_t)(sc * 128) * EMBED + tid * 4;
    const float* wb = weights + (size_t)bb * SEQ + sc * 128;

    float ax = 0.f, ay = 0.f, az = 0.f, aw = 0.f;
    #pragma unroll 4
    for (int s = 0; s < 128; ++s) {
        const float wgt = wb[s];
        const half4 h = *(const half4*)(xb + (size_t)s * EMBED);
        ax += wgt * (float)h[0]; ay += wgt * (float)h[1];
        az += wgt * (float)h[2]; aw += wgt * (float)h[3];
    }
    float* o = out + (size_t)bb * EMBED + tid * 4;
    atomicAdd(o + 0, ax);
    atomicAdd(o + 1, ay);
    atomicAdd(o + 2, az);
    atomicAdd(o + 3, aw);
}

// ---------------------------------------------------------------------------
extern "C" void kernel_launch(void* const* d_in, const int* in_sizes, int n_in,
                              void* d_out, int out_size, void* d_ws, size_t ws_size,
                              hipStream_t stream) {
    const float* x   = (const float*)d_in[0];
    const float* W   = (const float*)d_in[1];
    const float* b   = (const float*)d_in[2];
    const float* ctx = (const float*)d_in[3];
    float* out = (float*)d_out;

    char* ws = (char*)d_ws;
    _Float16* Wt      = (_Float16*)ws;                               // 2 MB
    float*    scores  = (float*)(ws + (2u << 20));                   // 256 KB
    float*    weights = (float*)(ws + (2u << 20) + (256u << 10));    // 256 KB
    _Float16* x16     = (_Float16*)(ws + (4u << 20));                // 128 MB

    const size_t need = (4ull << 20) + ((size_t)M_TOT * KDIM * 2);
    const bool fast = ws_size >= need;

    hipLaunchKernelGGL(transpose_w_kernel, dim3(32, 32), dim3(32, 8), 0, stream, W, Wt);
    hipLaunchKernelGGL(zero_kernel, dim3(M_TOT / 256), dim3(256), 0, stream, scores, out);

    if (fast) {
        hipLaunchKernelGGL(cvt_x_kernel, dim3(4096), dim3(256), 0, stream, x, x16);
        hipLaunchKernelGGL(score_gemm4, dim3(1024), dim3(512), 0, stream,
                           x16, Wt, b, ctx, scores);
    } else {
        hipLaunchKernelGGL(score_gemm_f32, dim3(4096), dim3(256), 0, stream,
                           x, Wt, b, ctx, scores);
    }

    hipLaunchKernelGGL(softmax_kernel, dim3(BATCH), dim3(256), 0, stream, scores, weights);

    if (fast) {
        hipLaunchKernelGGL(pool16_kernel, dim3(BATCH * 16), dim3(256), 0, stream,
                           x16, weights, out);
    } else {
        hipLaunchKernelGGL(pool_kernel, dim3(BATCH * 16), dim3(256), 0, stream,
                           x, weights, out);
    }
}

// Round 6
// 287.925 us; speedup vs baseline: 1.0181x; 1.0181x over previous
//
#include <hip/hip_runtime.h>
#include <hip/hip_bf16.h>

typedef _Float16 half8 __attribute__((ext_vector_type(8)));
typedef _Float16 half4 __attribute__((ext_vector_type(4)));
typedef float floatx4 __attribute__((ext_vector_type(4)));

#define EMBED 1024
#define SEQ   2048
#define BATCH 32
#define M_TOT (BATCH * SEQ)   // 65536 rows
#define KDIM  1024
#define NDIM  1024

// async global->LDS, 16B per lane, dest = wave-uniform base + lane*16
#define GLOAD16(g, l) __builtin_amdgcn_global_load_lds(                      \
    (const __attribute__((address_space(1))) void*)(g),                      \
    (__attribute__((address_space(3))) void*)(l), 16, 0, 0)

// ---------------------------------------------------------------------------
// Kernel 1: transpose + convert W[K][N] fp32 -> Wt[N][K] fp16
// ---------------------------------------------------------------------------
__global__ void transpose_w_kernel(const float* __restrict__ W,
                                   _Float16* __restrict__ Wt) {
    __shared__ float t[32][33];
    const int kt = blockIdx.x * 32;
    const int nt = blockIdx.y * 32;
    #pragma unroll
    for (int i = 0; i < 4; ++i)
        t[threadIdx.y + 8 * i][threadIdx.x] =
            W[(size_t)(kt + threadIdx.y + 8 * i) * NDIM + nt + threadIdx.x];
    __syncthreads();
    #pragma unroll
    for (int i = 0; i < 4; ++i)
        Wt[(size_t)(nt + threadIdx.y + 8 * i) * KDIM + kt + threadIdx.x] =
            (_Float16)t[threadIdx.x][threadIdx.y + 8 * i];
}

// ---------------------------------------------------------------------------
// Kernel 2: zero scores + out
// ---------------------------------------------------------------------------
__global__ void zero_kernel(float* __restrict__ scores, float* __restrict__ out) {
    const int i = blockIdx.x * 256 + threadIdx.x;
    if (i < M_TOT) scores[i] = 0.0f;
    if (i < BATCH * EMBED) out[i] = 0.0f;
}

// ---------------------------------------------------------------------------
// Kernel 2b: convert x fp32 -> fp16 (64M elements)
// ---------------------------------------------------------------------------
__global__ __launch_bounds__(256) void cvt_x_kernel(const float* __restrict__ x,
                                                    _Float16* __restrict__ x16) {
    const size_t stride = (size_t)gridDim.x * 256 * 8;
    for (size_t i = ((size_t)blockIdx.x * 256 + threadIdx.x) * 8;
         i < (size_t)M_TOT * KDIM; i += stride) {
        const float4 a = *(const float4*)(x + i);
        const float4 b = *(const float4*)(x + i + 4);
        half8 h;
        h[0] = (_Float16)a.x; h[1] = (_Float16)a.y; h[2] = (_Float16)a.z; h[3] = (_Float16)a.w;
        h[4] = (_Float16)b.x; h[5] = (_Float16)b.y; h[6] = (_Float16)b.z; h[7] = (_Float16)b.w;
        *(half8*)(x16 + i) = h;
    }
}

// ---------------------------------------------------------------------------
// Kernel 3: fused scores GEMM, 256x256 tile, BK=64, 8 waves (2Mx4N).
// 4 sub-phases per K-tile (16 MFMA each), 2 raw s_barriers per phase,
// counted s_waitcnt vmcnt(2) once per K-tile (never vmcnt(0) mid-loop).
// Each wave stages exactly the A-half (wm) and B-half (wn>>1) it reads:
// A pairs issued at ph0/ph1 (4-phase cover), B pairs at ph2/ph3 (Wt is
// L2-resident). LDS [128 rows][64 halves] units, XOR slot swizzle
// p = s ^ (row&7) via pre-swizzled global source + swizzled ds_read (m173).
// ---------------------------------------------------------------------------
__global__ __launch_bounds__(512, 2) void score_gemm5(
    const _Float16* __restrict__ x16, const _Float16* __restrict__ Wt,
    const float* __restrict__ bias, const float* __restrict__ ctx,
    float* __restrict__ scores) {
    __shared__ _Float16 As[2][2][128 * 64];   // [buf][M-half][rows 128][64 halves]
    __shared__ _Float16 Bs[2][2][128 * 64];   // [buf][N-half][rows 128][64 halves]

    const int tid  = threadIdx.x;
    const int lane = tid & 63;
    const int w    = tid >> 6;     // 0..7
    const int wm   = w >> 2;       // M-half of this wave
    const int wn   = w & 3;        // N-quarter
    const int wnh  = wn >> 1;      // N-half
    const int wnl  = wn & 1;

    // grid 1024 = 256 bm x 4 bn; XCD chunk swizzle (bijective 8 x 128)
    const int nb = ((blockIdx.x & 7) << 7) | (blockIdx.x >> 3);
    const int bm = nb >> 2;
    const int bn = nb & 3;

    // ---- staging geometry (per-wave-owned units) ----
    // A: wave stages rows [wn*32, wn*32+32) of M-half wm; 4 instrs x 8 rows.
    // B: wave stages rows [(wm*2+wnl)*32, +32) of N-half wnh.
    // lane l -> row +(l>>3), 16B slot l&7 linear in LDS; global slot
    // pre-swizzled s = (l&7) ^ (l>>3)  (both-sides XOR, rule 21).
    const int srow  = lane >> 3;
    const int gslot = (lane & 7) ^ srow;
    const int q2    = wm * 2 + wnl;
    const _Float16* Abase = x16 + (size_t)(bm * 256 + wm * 128 + wn * 32 + srow) * KDIM + gslot * 8;
    const _Float16* Bbase = Wt  + (size_t)(bn * 256 + wnh * 128 + q2 * 32 + srow) * KDIM + gslot * 8;

#define STAGE_A(d, kt1, i) GLOAD16(Abase + (size_t)(i) * 8 * KDIM + (kt1) * 64,  \
                                   &As[d][wm][(wn * 32 + (i) * 8) * 64])
#define STAGE_B(d, kt1, i) GLOAD16(Bbase + (size_t)(i) * 8 * KDIM + (kt1) * 64,  \
                                   &Bs[d][wnh][(q2 * 32 + (i) * 8) * 64])

    // ---- frag read geometry ----
    const int frow = lane & 15;
    const int fhi  = lane >> 4;       // 0..3
    const int fx   = frow & 7;        // XOR bits (row&7 == frow&7)

#define LD_A4(c, ks, mi0)                                                       \
    _Pragma("unroll")                                                           \
    for (int m = 0; m < 4; ++m)                                                 \
        afr[m] = *(const half8*)&As[c][wm][((mi0 + m) * 16 + frow) * 64 +       \
                                           ((((ks) * 4 + fhi) ^ fx) * 8)];
#define LD_B4(c, ks)                                                            \
    _Pragma("unroll")                                                           \
    for (int n = 0; n < 4; ++n)                                                 \
        bfr[n] = *(const half8*)&Bs[c][wnh][(wnl * 64 + n * 16 + frow) * 64 +   \
                                            ((((ks) * 4 + fhi) ^ fx) * 8)];
#define MFMA16(mi0)                                                             \
    __builtin_amdgcn_s_setprio(1);                                              \
    _Pragma("unroll")                                                           \
    for (int m = 0; m < 4; ++m)                                                 \
        _Pragma("unroll")                                                       \
        for (int n = 0; n < 4; ++n)                                             \
            acc[mi0 + m][n] = __builtin_amdgcn_mfma_f32_16x16x32_f16(           \
                afr[m], bfr[n], acc[mi0 + m][n], 0, 0, 0);                      \
    __builtin_amdgcn_s_setprio(0);

#define BAR() asm volatile("s_barrier" ::: "memory")

    // One K-tile, compile-time buffer parity c (compute) / d (stage dest).
    // STG: 1 = stage tile kt1, 0 = last tile (drain).
#define KTILE(c, d, kt1, STG, VMW)                                              \
    {                                                                           \
        /* ph0: A ks0 mi0-3 */                                                  \
        if (STG) { STAGE_A(d, kt1, 0); STAGE_A(d, kt1, 1); }                    \
        asm volatile(VMW ::: "memory");                                         \
        BAR();                                                                  \
        LD_B4(c, 0); LD_A4(c, 0, 0);                                            \
        MFMA16(0);                                                              \
        BAR();                                                                  \
        /* ph1: A ks0 mi4-7 */                                                  \
        LD_A4(c, 0, 4);                                                         \
        if (STG) { STAGE_A(d, kt1, 2); STAGE_A(d, kt1, 3); }                    \
        BAR();                                                                  \
        MFMA16(4);                                                              \
        BAR();                                                                  \
        /* ph2: ks1 mi0-3 */                                                    \
        LD_B4(c, 1); LD_A4(c, 1, 0);                                            \
        if (STG) { STAGE_B(d, kt1, 0); STAGE_B(d, kt1, 1); }                    \
        BAR();                                                                  \
        MFMA16(0 + 0);                                                          \
        BAR();                                                                  \
        /* ph3: ks1 mi4-7 */                                                    \
        LD_A4(c, 1, 4);                                                         \
        if (STG) { STAGE_B(d, kt1, 2); STAGE_B(d, kt1, 3); }                    \
        BAR();                                                                  \
        MFMA16(4);                                                              \
        BAR();                                                                  \
    }

    floatx4 acc[8][4] = {};
    half8 afr[4], bfr[4];

    // prologue: burst-stage tile 0 into buf 0
    #pragma unroll
    for (int i = 0; i < 4; ++i) STAGE_A(0, 0, i);
    #pragma unroll
    for (int i = 0; i < 4; ++i) STAGE_B(0, 0, i);

    // kt = 0..13 (paired for compile-time parity), stage kt+1
    for (int kt2 = 0; kt2 < 7; ++kt2) {
        const int kt = kt2 * 2;
        KTILE(0, 1, kt + 1, 1, "s_waitcnt vmcnt(2)");
        KTILE(1, 0, kt + 2, 1, "s_waitcnt vmcnt(2)");
    }
    // kt = 14: stage tile 15; kt = 15: drain
    KTILE(0, 1, 15, 1, "s_waitcnt vmcnt(2)");
    KTILE(1, 0, 0, 0, "s_waitcnt vmcnt(0)");

#undef KTILE
#undef BAR
#undef MFMA16
#undef LD_B4
#undef LD_A4
#undef STAGE_B
#undef STAGE_A

    // ---- epilogue: fast tanh + ctx dot + 16-lane reduce + atomic ----
    float bv[4], cv[4];
    #pragma unroll
    for (int ni = 0; ni < 4; ++ni) {
        const int col = bn * 256 + wn * 64 + ni * 16 + frow;
        bv[ni] = bias[col];
        cv[ni] = ctx[col];
    }
    #pragma unroll
    for (int mi = 0; mi < 8; ++mi) {
        #pragma unroll
        for (int j = 0; j < 4; ++j) {
            float partial = 0.0f;
            #pragma unroll
            for (int ni = 0; ni < 4; ++ni) {
                const float v = acc[mi][ni][j] + bv[ni];
                const float e = __expf(2.0f * v);          // tanh(v)=1-2/(e^{2v}+1)
                const float t = 1.0f - 2.0f * __builtin_amdgcn_rcpf(e + 1.0f);
                partial += t * cv[ni];
            }
            #pragma unroll
            for (int off = 1; off < 16; off <<= 1)
                partial += __shfl_xor(partial, off, 64);
            if (frow == 0) {
                const int rowg = bm * 256 + wm * 128 + mi * 16 + fhi * 4 + j;
                atomicAdd(&scores[rowg], partial);
            }
        }
    }
}

// ---------------------------------------------------------------------------
// Fallback GEMM (ws too small for x16): reg-staged fp32 path.
// ---------------------------------------------------------------------------
__global__ __launch_bounds__(256) void score_gemm_f32(
    const float* __restrict__ A32p, const _Float16* __restrict__ Wt,
    const float* __restrict__ bias, const float* __restrict__ ctx,
    float* __restrict__ scores) {
    __shared__ _Float16 As[128 * 64];
    __shared__ _Float16 Bs[128 * 64];

    const int bid = blockIdx.x;
    const int bm = bid >> 3;
    const int bn = bid & 7;
    const int tid = threadIdx.x;
    const int lane = tid & 63;
    const int wid = tid >> 6;
    const int wm = wid >> 1;
    const int wn = wid & 1;

    const int c = tid & 7;
    const int r0 = tid >> 3;
    const int swz = (r0 & 7) << 3;
    const int wcol = (c * 8) ^ swz;

    float4 aF[4][2];
    int4   bR[4];

    #pragma unroll
    for (int i = 0; i < 4; ++i) {
        const int row = r0 + 32 * i;
        const float* p = A32p + (size_t)(bm * 128 + row) * KDIM + c * 8;
        aF[i][0] = *(const float4*)p;
        aF[i][1] = *(const float4*)(p + 4);
        bR[i] = *(const int4*)(Wt + (size_t)(bn * 128 + row) * KDIM + c * 8);
    }

    floatx4 acc[4][4] = {};

    for (int kt = 0; kt < KDIM / 64; ++kt) {
        __syncthreads();
        #pragma unroll
        for (int i = 0; i < 4; ++i) {
            const int row = r0 + 32 * i;
            half8 h;
            h[0] = (_Float16)aF[i][0].x; h[1] = (_Float16)aF[i][0].y;
            h[2] = (_Float16)aF[i][0].z; h[3] = (_Float16)aF[i][0].w;
            h[4] = (_Float16)aF[i][1].x; h[5] = (_Float16)aF[i][1].y;
            h[6] = (_Float16)aF[i][1].z; h[7] = (_Float16)aF[i][1].w;
            *(half8*)&As[row * 64 + wcol] = h;
            *(int4*)&Bs[row * 64 + wcol] = bR[i];
        }
        __syncthreads();

        if (kt + 1 < KDIM / 64) {
            #pragma unroll
            for (int i = 0; i < 4; ++i) {
                const int row = r0 + 32 * i;
                const float* p = A32p + (size_t)(bm * 128 + row) * KDIM + (kt + 1) * 64 + c * 8;
                aF[i][0] = *(const float4*)p;
                aF[i][1] = *(const float4*)(p + 4);
                bR[i] = *(const int4*)(Wt + (size_t)(bn * 128 + row) * KDIM + (kt + 1) * 64 + c * 8);
            }
        }

        #pragma unroll
        for (int s = 0; s < 2; ++s) {
            half8 afr[4], bfr[4];
            const int colr = s * 32 + (lane >> 4) * 8;
            #pragma unroll
            for (int m = 0; m < 4; ++m) {
                const int row = wm * 64 + m * 16 + (lane & 15);
                afr[m] = *(const half8*)&As[row * 64 + (colr ^ ((row & 7) << 3))];
            }
            #pragma unroll
            for (int n = 0; n < 4; ++n) {
                const int row = wn * 64 + n * 16 + (lane & 15);
                bfr[n] = *(const half8*)&Bs[row * 64 + (colr ^ ((row & 7) << 3))];
            }
            #pragma unroll
            for (int m = 0; m < 4; ++m)
                #pragma unroll
                for (int n = 0; n < 4; ++n)
                    acc[m][n] = __builtin_amdgcn_mfma_f32_16x16x32_f16(
                        afr[m], bfr[n], acc[m][n], 0, 0, 0);
        }
    }

    float bv[4], cv[4];
    #pragma unroll
    for (int n = 0; n < 4; ++n) {
        const int col = bn * 128 + wn * 64 + n * 16 + (lane & 15);
        bv[n] = bias[col];
        cv[n] = ctx[col];
    }
    #pragma unroll
    for (int m = 0; m < 4; ++m) {
        #pragma unroll
        for (int j = 0; j < 4; ++j) {
            float partial = 0.0f;
            #pragma unroll
            for (int n = 0; n < 4; ++n) {
                const float v = acc[m][n][j] + bv[n];
                const float e = __expf(2.0f * v);
                const float t = 1.0f - 2.0f * __builtin_amdgcn_rcpf(e + 1.0f);
                partial += t * cv[n];
            }
            #pragma unroll
            for (int off = 1; off < 16; off <<= 1)
                partial += __shfl_xor(partial, off, 64);
            if ((lane & 15) == 0) {
                const int rowg = bm * 128 + wm * 64 + m * 16 + (lane >> 4) * 4 + j;
                atomicAdd(&scores[rowg], partial);
            }
        }
    }
}

// ---------------------------------------------------------------------------
// Kernel 4: softmax over seq dim per batch. 32 blocks x 256 threads.
// ---------------------------------------------------------------------------
__global__ void softmax_kernel(const float* __restrict__ scores,
                               float* __restrict__ weights) {
    const int bb = blockIdx.x;
    const int tid = threadIdx.x;
    const float* s = scores + (size_t)bb * SEQ;
    float* w = weights + (size_t)bb * SEQ;

    __shared__ float red[8];

    float v[8];
    float mx = -1e30f;
    #pragma unroll
    for (int i = 0; i < 8; ++i) {
        v[i] = s[tid + i * 256];
        mx = fmaxf(mx, v[i]);
    }
    #pragma unroll
    for (int off = 1; off < 64; off <<= 1)
        mx = fmaxf(mx, __shfl_xor(mx, off, 64));
    const int wv = tid >> 6;
    if ((tid & 63) == 0) red[wv] = mx;
    __syncthreads();
    mx = fmaxf(fmaxf(red[0], red[1]), fmaxf(red[2], red[3]));

    float sum = 0.0f;
    #pragma unroll
    for (int i = 0; i < 8; ++i) {
        v[i] = __expf(v[i] - mx);
        sum += v[i];
    }
    #pragma unroll
    for (int off = 1; off < 64; off <<= 1)
        sum += __shfl_xor(sum, off, 64);
    if ((tid & 63) == 0) red[4 + wv] = sum;
    __syncthreads();
    sum = red[4] + red[5] + red[6] + red[7];
    const float inv = 1.0f / sum;
    #pragma unroll
    for (int i = 0; i < 8; ++i)
        w[tid + i * 256] = v[i] * inv;
}

// ---------------------------------------------------------------------------
// Kernel 5: weighted pooling (fp32 fallback).
// ---------------------------------------------------------------------------
__global__ __launch_bounds__(256) void pool_kernel(const float* __restrict__ x,
                                                   const float* __restrict__ weights,
                                                   float* __restrict__ out) {
    const int bb = blockIdx.x >> 4;
    const int sc = blockIdx.x & 15;
    const int tid = threadIdx.x;

    const float4* xb = (const float4*)(x + (size_t)bb * SEQ * EMBED) +
                       (size_t)(sc * 128) * (EMBED / 4) + tid;
    const float* wb = weights + (size_t)bb * SEQ + sc * 128;

    float ax = 0.f, ay = 0.f, az = 0.f, aw = 0.f;
    #pragma unroll 4
    for (int s = 0; s < 128; ++s) {
        const float wgt = wb[s];
        const float4 xv = xb[(size_t)s * (EMBED / 4)];
        ax += wgt * xv.x; ay += wgt * xv.y; az += wgt * xv.z; aw += wgt * xv.w;
    }
    float* o = out + (size_t)bb * EMBED + tid * 4;
    atomicAdd(o + 0, ax);
    atomicAdd(o + 1, ay);
    atomicAdd(o + 2, az);
    atomicAdd(o + 3, aw);
}

// ---------------------------------------------------------------------------
// Kernel 5b: weighted pooling (fp16 x16) — halves the read bytes.
// ---------------------------------------------------------------------------
__global__ __launch_bounds__(256) void pool16_kernel(const _Float16* __restrict__ x16,
                                                     const float* __restrict__ weights,
                                                     float* __restrict__ out) {
    const int bb = blockIdx.x >> 4;
    const int sc = blockIdx.x & 15;
    const int tid = threadIdx.x;

    const _Float16* xb = x16 + (size_t)bb * SEQ * EMBED +
                         (size_t)(sc * 128) * EMBED + tid * 4;
    const float* wb = weights + (size_t)bb * SEQ + sc * 128;

    float ax = 0.f, ay = 0.f, az = 0.f, aw = 0.f;
    #pragma unroll 4
    for (int s = 0; s < 128; ++s) {
        const float wgt = wb[s];
        const half4 h = *(const half4*)(xb + (size_t)s * EMBED);
        ax += wgt * (float)h[0]; ay += wgt * (float)h[1];
        az += wgt * (float)h[2]; aw += wgt * (float)h[3];
    }
    float* o = out + (size_t)bb * EMBED + tid * 4;
    atomicAdd(o + 0, ax);
    atomicAdd(o + 1, ay);
    atomicAdd(o + 2, az);
    atomicAdd(o + 3, aw);
}

// ---------------------------------------------------------------------------
extern "C" void kernel_launch(void* const* d_in, const int* in_sizes, int n_in,
                              void* d_out, int out_size, void* d_ws, size_t ws_size,
                              hipStream_t stream) {
    const float* x   = (const float*)d_in[0];
    const float* W   = (const float*)d_in[1];
    const float* b   = (const float*)d_in[2];
    const float* ctx = (const float*)d_in[3];
    float* out = (float*)d_out;

    char* ws = (char*)d_ws;
    _Float16* Wt      = (_Float16*)ws;                               // 2 MB
    float*    scores  = (float*)(ws + (2u << 20));                   // 256 KB
    float*    weights = (float*)(ws + (2u << 20) + (256u << 10));    // 256 KB
    _Float16* x16     = (_Float16*)(ws + (4u << 20));                // 128 MB

    const size_t need = (4ull << 20) + ((size_t)M_TOT * KDIM * 2);
    const bool fast = ws_size >= need;

    hipLaunchKernelGGL(transpose_w_kernel, dim3(32, 32), dim3(32, 8), 0, stream, W, Wt);
    hipLaunchKernelGGL(zero_kernel, dim3(M_TOT / 256), dim3(256), 0, stream, scores, out);

    if (fast) {
        hipLaunchKernelGGL(cvt_x_kernel, dim3(4096), dim3(256), 0, stream, x, x16);
        hipLaunchKernelGGL(score_gemm5, dim3(1024), dim3(512), 0, stream,
                           x16, Wt, b, ctx, scores);
    } else {
        hipLaunchKernelGGL(score_gemm_f32, dim3(4096), dim3(256), 0, stream,
                           x, Wt, b, ctx, scores);
    }

    hipLaunchKernelGGL(softmax_kernel, dim3(BATCH), dim3(256), 0, stream, scores, weights);

    if (fast) {
        hipLaunchKernelGGL(pool16_kernel, dim3(BATCH * 16), dim3(256), 0, stream,
                           x16, weights, out);
    } else {
        hipLaunchKernelGGL(pool_kernel, dim3(BATCH * 16), dim3(256), 0, stream,
                           x, weights, out);
    }
}